// Round 3
// baseline (560.601 us; speedup 1.0000x reference)
//
#include <hip/hip_runtime.h>
#include <hip/hip_bf16.h>
#include <stdint.h>

#define NQ 128
#define NLVL 5

typedef float  floatx4 __attribute__((ext_vector_type(4)));
typedef short  short8  __attribute__((ext_vector_type(8)));

__device__ __forceinline__ uint16_t f2bf(float f) {
    uint32_t u = __builtin_bit_cast(uint32_t, f);
    uint32_t r = u + 0x7FFFu + ((u >> 16) & 1u);   // RNE
    return (uint16_t)(r >> 16);
}
__device__ __forceinline__ uint32_t pk2bf(float a, float b) {
    return (uint32_t)f2bf(a) | ((uint32_t)f2bf(b) << 16);
}
__device__ __forceinline__ float bf_lo(uint32_t p) {   // low bf16 -> f32
    return __builtin_bit_cast(float, p << 16);
}
__device__ __forceinline__ float bf_hi(uint32_t p) {   // high bf16 -> f32
    return __builtin_bit_cast(float, p & 0xFFFF0000u);
}

// ---------------------------------------------------------------- configs ----
struct LvlCfg {
    const float* x;       // (N, C, HW)
    float*       part;    // partial G tiles: (((n*nch+ch)*nt+ti)*nt+tj)*R*R
    uint16_t*    smT;     // (NQ, C) bf16, K-contiguous
    const float* smN;     // (C, NQ) fp32, o-contiguous
    int C, HW, nt, R, nch, chunkH, ksteps;
    int gramBase, qformBase;
};
struct GramParams { LvlCfg l[NLVL]; };

// ---------------------------------------------------------------- softmax ----
struct SmParams {
    const float* w[NLVL];
    uint16_t*    smT[NLVL];
    float*       smN[NLVL];
    int          C[NLVL];
};

__global__ __launch_bounds__(64) void softmax_kernel(SmParams p) {
    int b   = blockIdx.x;      // 5*128 blocks
    int lvl = b >> 7;
    int o   = b & 127;
    int C   = p.C[lvl];
    const float* w = p.w[lvl];
    int lane = threadIdx.x;
    float ev[8];
    int nIter = C >> 6;
    float mx = -1e30f;
    for (int it = 0; it < nIter; ++it) {
        float z = 10.0f * w[(size_t)(it * 64 + lane) * NQ + o];
        ev[it] = z;
        mx = fmaxf(mx, z);
    }
    #pragma unroll
    for (int s = 32; s; s >>= 1) mx = fmaxf(mx, __shfl_xor(mx, s));
    float sum = 0.f;
    for (int it = 0; it < nIter; ++it) { ev[it] = expf(ev[it] - mx); sum += ev[it]; }
    #pragma unroll
    for (int s = 32; s; s >>= 1) sum += __shfl_xor(sum, s);
    float inv = 1.0f / sum;
    uint16_t* dstT = p.smT[lvl] + (size_t)o * C;
    float*    dstN = p.smN[lvl];
    for (int it = 0; it < nIter; ++it) {
        float v = ev[it] * inv;
        int c = it * 64 + lane;
        dstT[c] = f2bf(v);
        dstN[(size_t)c * NQ + o] = v;
    }
}

// --------------------------------------------------------------- w transpose -
struct TrCfg { const float* src; float* dst; int K, O, base; };
struct TrParams { TrCfg m[3]; };

__global__ __launch_bounds__(256) void wtrans_kernel(TrParams p) {
    __shared__ float tile[32][33];
    int bid = blockIdx.x;
    int mi = 0;
    #pragma unroll
    for (int i = 1; i < 3; ++i) if (bid >= p.m[i].base) mi = i;
    TrCfg c = p.m[mi];
    int rel = bid - c.base;
    int ox = c.O >> 5;
    int ty = rel / ox, tx = rel - ty * ox;
    int k0 = ty * 32, o0 = tx * 32;
    int t = threadIdx.x;
    int lr = t >> 5;        // 0..7
    int lc = t & 31;
    #pragma unroll
    for (int i = 0; i < 4; ++i)
        tile[lr + 8 * i][lc] = c.src[(size_t)(k0 + lr + 8 * i) * c.O + o0 + lc];
    __syncthreads();
    #pragma unroll
    for (int i = 0; i < 4; ++i)
        c.dst[(size_t)(o0 + lr + 8 * i) * c.K + k0 + lc] = tile[lc][lr + 8 * i];
}

// ------------------------------------------------------------------- gram ----
// G[c,c'] = sum_h x[c,h] x[c',h] : contraction over contiguous h.
// Block = (lvl, n, h-chunk, tile_i, tile_j). Tiles R x R (R=64 lvl0, else 128).
__global__ __launch_bounds__(256) void gram_kernel(GramParams p) {
    __shared__ __align__(16) short At[128 * 40];
    __shared__ __align__(16) short Bt[128 * 40];

    int bid = blockIdx.x;
    int lvl = 0;
    #pragma unroll
    for (int i = 1; i < NLVL; ++i) if (bid >= p.l[i].gramBase) lvl = i;
    LvlCfg cf = p.l[lvl];
    int rel  = bid - cf.gramBase;
    int ntt  = cf.nt * cf.nt;
    int pern = cf.nch * ntt;
    int n  = rel / pern;        int r2 = rel - n * pern;
    int ch = r2 / ntt;          int r3 = r2 - ch * ntt;
    int ti = r3 / cf.nt;        int tj = r3 - ti * cf.nt;
    bool diag = (ti == tj);
    int R = cf.R;

    const float* xa = cf.x + ((size_t)n * cf.C + ti * 128) * cf.HW + (size_t)ch * cf.chunkH;
    const float* xb = cf.x + ((size_t)n * cf.C + tj * 128) * cf.HW + (size_t)ch * cf.chunkH;

    int t = threadIdx.x, wave = t >> 6, lane = t & 63;
    int m = lane & 15, kg = lane >> 4;
    int fc = t >> 3;            // staging row base
    int fh = (t & 7) * 4;       // staging h offset (floats) == short offset in row

    floatx4 acc[2][8];
    #pragma unroll
    for (int i = 0; i < 2; ++i)
        #pragma unroll
        for (int j = 0; j < 8; ++j) acc[i][j] = (floatx4){0.f, 0.f, 0.f, 0.f};

    int aIt    = R >> 5;        // 2 or 4 staging iters
    int mtCnt  = R >> 6;        // 1 or 2
    int mtBase = wave * mtCnt;
    int otCnt  = R >> 4;        // 4 or 8

    for (int st = 0; st < cf.ksteps; ++st) {
        const float* pa = xa + st * 32 + fh;
        floatx4 va[4], vb[4];
        #pragma unroll
        for (int i = 0; i < 4; ++i) if (i < aIt)
            va[i] = *(const floatx4*)(pa + (size_t)(fc + 32 * i) * cf.HW);
        if (!diag) {
            const float* pb = xb + st * 32 + fh;
            #pragma unroll
            for (int i = 0; i < 4; ++i) if (i < aIt)
                vb[i] = *(const floatx4*)(pb + (size_t)(fc + 32 * i) * cf.HW);
        }
        #pragma unroll
        for (int i = 0; i < 4; ++i) if (i < aIt) {
            uint2 u; u.x = pk2bf(va[i].x, va[i].y); u.y = pk2bf(va[i].z, va[i].w);
            *(uint2*)&At[(fc + 32 * i) * 40 + fh] = u;
        }
        if (!diag) {
            #pragma unroll
            for (int i = 0; i < 4; ++i) if (i < aIt) {
                uint2 u; u.x = pk2bf(vb[i].x, vb[i].y); u.y = pk2bf(vb[i].z, vb[i].w);
                *(uint2*)&Bt[(fc + 32 * i) * 40 + fh] = u;
            }
        }
        __syncthreads();

        const short* Bsrc = diag ? At : Bt;
        short8 af[2];
        #pragma unroll
        for (int mt = 0; mt < 2; ++mt) if (mt < mtCnt)
            af[mt] = *(const short8*)&At[((mtBase + mt) * 16 + m) * 40 + kg * 8];
        #pragma unroll
        for (int ot = 0; ot < 8; ++ot) if (ot < otCnt) {
            short8 b8 = *(const short8*)&Bsrc[(ot * 16 + m) * 40 + kg * 8];
            #pragma unroll
            for (int mt = 0; mt < 2; ++mt) if (mt < mtCnt)
                acc[mt][ot] = __builtin_amdgcn_mfma_f32_16x16x32_bf16(
                    af[mt], b8, acc[mt][ot], 0, 0, 0);
        }
        __syncthreads();
    }

    // store partial tile (plain coalesced stores, no atomics)
    size_t tileElems = (size_t)R * R;
    float* pd = cf.part + (((size_t)(n * cf.nch + ch) * cf.nt + ti) * cf.nt + tj) * tileElems;
    #pragma unroll
    for (int mt = 0; mt < 2; ++mt) if (mt < mtCnt)
        #pragma unroll
        for (int ot = 0; ot < 8; ++ot) if (ot < otCnt)
            #pragma unroll
            for (int r = 0; r < 4; ++r) {
                int row = (mtBase + mt) * 16 + kg * 4 + r;
                int col = ot * 16 + m;
                pd[(size_t)row * R + col] = acc[mt][ot][r];
            }
}

// ------------------------------------------------------------------ qform ----
// T = G @ smT  (K = c', G summed over chunks, split hi/lo bf16),
// quad[o] += sum_c sm[c,o] * T[c,o]
__global__ __launch_bounds__(256) void qform_kernel(GramParams p, float* quad) {
    __shared__ __align__(16) short Ahi[128 * 40];
    __shared__ __align__(16) short Alo[128 * 40];
    __shared__ __align__(16) short Bs [128 * 40];

    int bid = blockIdx.x;
    int lvl = 0;
    #pragma unroll
    for (int i = 1; i < NLVL; ++i) if (bid >= p.l[i].qformBase) lvl = i;
    LvlCfg cf = p.l[lvl];
    int rel = bid - cf.qformBase;
    int n  = rel / cf.nt;
    int mb = rel - n * cf.nt;
    int R = cf.R;

    int t = threadIdx.x, wave = t >> 6, lane = t & 63;
    int m = lane & 15, kg = lane >> 4;
    int aIt    = R >> 5;
    int mtCnt  = R >> 6;
    int mtBase = wave * mtCnt;

    floatx4 acc[2][8];
    #pragma unroll
    for (int i = 0; i < 2; ++i)
        #pragma unroll
        for (int j = 0; j < 8; ++j) acc[i][j] = (floatx4){0.f, 0.f, 0.f, 0.f};

    size_t tileElems = (size_t)R * R;
    size_t chStride  = (size_t)cf.nt * cf.nt * tileElems;

    for (int ks = 0; ks < cf.C; ks += 32) {
        int tjk = ks >> 7;
        int kin = ks & 127;
        // ---- A staging: sum partial chunks, split hi/lo bf16
        #pragma unroll
        for (int i = 0; i < 4; ++i) if (i < aIt) {
            int row = (t >> 3) + 32 * i;
            int k4  = (t & 7) * 4;
            const float* src = cf.part
                + (((size_t)n * cf.nch * cf.nt + mb) * cf.nt + tjk) * tileElems
                + (size_t)row * R + kin + k4;
            floatx4 s0 = {0,0,0,0}, s1 = {0,0,0,0}, s2 = {0,0,0,0}, s3 = {0,0,0,0};
            int ch = 0;
            for (; ch + 4 <= cf.nch; ch += 4) {
                s0 += *(const floatx4*)(src + (size_t)ch * chStride);
                s1 += *(const floatx4*)(src + (size_t)(ch + 1) * chStride);
                s2 += *(const floatx4*)(src + (size_t)(ch + 2) * chStride);
                s3 += *(const floatx4*)(src + (size_t)(ch + 3) * chStride);
            }
            for (; ch < cf.nch; ++ch) s0 += *(const floatx4*)(src + (size_t)ch * chStride);
            floatx4 s = (s0 + s1) + (s2 + s3);
            uint32_t h0 = pk2bf(s.x, s.y), h1 = pk2bf(s.z, s.w);
            floatx4 resid;
            resid.x = s.x - bf_lo(h0); resid.y = s.y - bf_hi(h0);
            resid.z = s.z - bf_lo(h1); resid.w = s.w - bf_hi(h1);
            uint32_t l0 = pk2bf(resid.x, resid.y), l1 = pk2bf(resid.z, resid.w);
            uint2 uh; uh.x = h0; uh.y = h1;
            uint2 ul; ul.x = l0; ul.y = l1;
            *(uint2*)&Ahi[row * 40 + k4] = uh;
            *(uint2*)&Alo[row * 40 + k4] = ul;
        }
        // ---- B staging: smT[o][ks..ks+32) bf16 ; 128 rows x 4 uint4 = 512 slots
        #pragma unroll
        for (int it = 0; it < 2; ++it) {
            int idx  = it * 256 + t;
            int o    = idx >> 2;
            int part = idx & 3;
            uint4 v = *(const uint4*)(cf.smT + (size_t)o * cf.C + ks + part * 8);
            *(uint4*)&Bs[o * 40 + part * 8] = v;
        }
        __syncthreads();

        short8 ah[2], al[2];
        #pragma unroll
        for (int mt = 0; mt < 2; ++mt) if (mt < mtCnt) {
            ah[mt] = *(const short8*)&Ahi[((mtBase + mt) * 16 + m) * 40 + kg * 8];
            al[mt] = *(const short8*)&Alo[((mtBase + mt) * 16 + m) * 40 + kg * 8];
        }
        #pragma unroll
        for (int ot = 0; ot < 8; ++ot) {
            short8 b8 = *(const short8*)&Bs[(ot * 16 + m) * 40 + kg * 8];
            #pragma unroll
            for (int mt = 0; mt < 2; ++mt) if (mt < mtCnt) {
                acc[mt][ot] = __builtin_amdgcn_mfma_f32_16x16x32_bf16(ah[mt], b8, acc[mt][ot], 0, 0, 0);
                acc[mt][ot] = __builtin_amdgcn_mfma_f32_16x16x32_bf16(al[mt], b8, acc[mt][ot], 0, 0, 0);
            }
        }
        __syncthreads();
    }

    // ---- epilogue: quad[o] += sum_c sm[c,o] * T[c,o]
    const float* smN = cf.smN;
    float* qb = quad + (size_t)(lvl * 8 + n) * NQ;
    #pragma unroll
    for (int ot = 0; ot < 8; ++ot) {
        float s = 0.f;
        #pragma unroll
        for (int mt = 0; mt < 2; ++mt) if (mt < mtCnt)
            #pragma unroll
            for (int r = 0; r < 4; ++r) {
                int c = mb * 128 + (mtBase + mt) * 16 + kg * 4 + r;
                int o = ot * 16 + m;
                s = fmaf(acc[mt][ot][r], smN[(size_t)c * NQ + o], s);
            }
        s += __shfl_xor(s, 16);
        s += __shfl_xor(s, 32);
        if (lane < 16) atomicAdd(qb + ot * 16 + lane, s);
    }
}

// ------------------------------------------------------------------- head ----
__device__ __forceinline__ float block_sum512(float v, float* red8, int t) {
    #pragma unroll
    for (int s = 32; s; s >>= 1) v += __shfl_xor(v, s);
    __syncthreads();
    if ((t & 63) == 0) red8[t >> 6] = v;
    __syncthreads();
    float tot = 0.f;
    #pragma unroll
    for (int i = 0; i < 8; ++i) tot += red8[i];
    return tot;
}

__global__ __launch_bounds__(512) void head_kernel(
    const float* __restrict__ quad,
    const float* __restrict__ wt1, const float* __restrict__ fc1_b,
    const float* __restrict__ wt2, const float* __restrict__ fc2_b,
    const float* __restrict__ wt3, const float* __restrict__ fc3_b,
    float* __restrict__ out) {
    __shared__ float feat[640];
    __shared__ float hbuf[512];
    __shared__ float red8[8];
    __shared__ float stats[10];
    int n = blockIdx.x;
    int t = threadIdx.x;

    for (int idx = t; idx < 640; idx += 512) {
        int lvl = idx >> 7, o = idx & 127;
        feat[idx] = quad[(size_t)(lvl * 8 + n) * NQ + o];
    }
    __syncthreads();
    if (t < 5) {
        float s = 0.f;
        for (int i = 0; i < 128; ++i) s += feat[t * 128 + i];
        float mean = s * (1.f / 128.f);
        float v = 0.f;
        for (int i = 0; i < 128; ++i) { float d = feat[t * 128 + i] - mean; v += d * d; }
        stats[t]     = mean;
        stats[5 + t] = sqrtf(v * (1.f / 127.f)) + 1e-8f;
    }
    __syncthreads();
    for (int idx = t; idx < 640; idx += 512) {
        int lvl = idx >> 7;
        feat[idx] = (feat[idx] - stats[lvl]) / stats[5 + lvl];
    }
    __syncthreads();

    // fc1 (640 -> 512), K-contiguous transposed weights
    float acc = fc1_b[t];
    {
        const float* wr = wt1 + (size_t)t * 640;
        #pragma unroll 4
        for (int k = 0; k < 640; k += 4) {
            floatx4 wv = *(const floatx4*)(wr + k);
            floatx4 fv = *(const floatx4*)&feat[k];
            acc = fmaf(wv.x, fv.x, acc); acc = fmaf(wv.y, fv.y, acc);
            acc = fmaf(wv.z, fv.z, acc); acc = fmaf(wv.w, fv.w, acc);
        }
    }
    float mean = block_sum512(acc, red8, t) * (1.f / 512.f);
    float d    = acc - mean;
    float var  = block_sum512(d * d, red8, t) * (1.f / 511.f);
    float nv   = d / (sqrtf(var) + 1e-8f);
    __syncthreads();
    hbuf[t] = nv > 0.f ? nv : 0.01f * nv;
    __syncthreads();

    // fc2 (512 -> 512)
    float acc2 = fc2_b[t];
    {
        const float* wr = wt2 + (size_t)t * 512;
        #pragma unroll 4
        for (int k = 0; k < 512; k += 4) {
            floatx4 wv = *(const floatx4*)(wr + k);
            floatx4 fv = *(const floatx4*)&hbuf[k];
            acc2 = fmaf(wv.x, fv.x, acc2); acc2 = fmaf(wv.y, fv.y, acc2);
            acc2 = fmaf(wv.z, fv.z, acc2); acc2 = fmaf(wv.w, fv.w, acc2);
        }
    }
    mean = block_sum512(acc2, red8, t) * (1.f / 512.f);
    d    = acc2 - mean;
    var  = block_sum512(d * d, red8, t) * (1.f / 511.f);
    nv   = d / (sqrtf(var) + 1e-8f);
    __syncthreads();
    hbuf[t] = nv > 0.f ? nv : 0.01f * nv;
    __syncthreads();

    // fc3 (512 -> 128)
    if (t < 128) {
        float acc3 = fc3_b[t];
        const float* wr = wt3 + (size_t)t * 512;
        #pragma unroll 4
        for (int k = 0; k < 512; k += 4) {
            floatx4 wv = *(const floatx4*)(wr + k);
            floatx4 fv = *(const floatx4*)&hbuf[k];
            acc3 = fmaf(wv.x, fv.x, acc3); acc3 = fmaf(wv.y, fv.y, acc3);
            acc3 = fmaf(wv.z, fv.z, acc3); acc3 = fmaf(wv.w, fv.w, acc3);
        }
        out[(size_t)n * NQ + t] = acc3;
    }
}

// ----------------------------------------------------------------- launch ----
extern "C" void kernel_launch(void* const* d_in, const int* in_sizes, int n_in,
                              void* d_out, int out_size, void* d_ws, size_t ws_size,
                              hipStream_t stream) {
    static const int Cs  [NLVL] = {64, 128, 256, 512, 512};
    static const int HWs [NLVL] = {65536, 16384, 4096, 1024, 256};
    static const int NTs [NLVL] = {1, 1, 2, 4, 4};
    static const int Rs  [NLVL] = {64, 128, 128, 128, 128};
    static const int NCHs[NLVL] = {32, 8, 4, 1, 1};

    const float* x[NLVL];
    const float* w[NLVL];
    for (int i = 0; i < NLVL; ++i) {
        x[i] = (const float*)d_in[2 * i];
        w[i] = (const float*)d_in[2 * i + 1];
    }
    const float* fc1_w = (const float*)d_in[10];
    const float* fc1_b = (const float*)d_in[11];
    const float* fc2_w = (const float*)d_in[12];
    const float* fc2_b = (const float*)d_in[13];
    const float* fc3_w = (const float*)d_in[14];
    const float* fc3_b = (const float*)d_in[15];

    // ---- workspace layout
    char* ws = (char*)d_ws;
    size_t off = 0;
    float* part[NLVL];
    for (int l = 0; l < NLVL; ++l) {
        part[l] = (float*)(ws + off);
        off += (size_t)8 * NCHs[l] * NTs[l] * NTs[l] * Rs[l] * Rs[l] * sizeof(float);
    }
    uint16_t* smT[NLVL];
    for (int l = 0; l < NLVL; ++l) { smT[l] = (uint16_t*)(ws + off); off += (size_t)Cs[l] * NQ * sizeof(uint16_t); }
    off = (off + 15) & ~(size_t)15;
    float* smN[NLVL];
    for (int l = 0; l < NLVL; ++l) { smN[l] = (float*)(ws + off); off += (size_t)Cs[l] * NQ * sizeof(float); }
    float* wt1 = (float*)(ws + off); off += (size_t)512 * 640 * sizeof(float);
    float* wt2 = (float*)(ws + off); off += (size_t)512 * 512 * sizeof(float);
    float* wt3 = (float*)(ws + off); off += (size_t)128 * 512 * sizeof(float);
    float* quad = (float*)(ws + off); off += (size_t)NLVL * 8 * NQ * sizeof(float);
    (void)ws_size;  // needs ~36.3 MB

    // ---- params
    SmParams sp;
    for (int l = 0; l < NLVL; ++l) { sp.w[l] = w[l]; sp.smT[l] = smT[l]; sp.smN[l] = smN[l]; sp.C[l] = Cs[l]; }

    GramParams gp;
    int gBase = 0, qBase = 0;
    for (int l = 0; l < NLVL; ++l) {
        LvlCfg& c = gp.l[l];
        c.x = x[l]; c.part = part[l]; c.smT = smT[l]; c.smN = smN[l];
        c.C = Cs[l]; c.HW = HWs[l]; c.nt = NTs[l]; c.R = Rs[l];
        c.nch = NCHs[l]; c.chunkH = HWs[l] / NCHs[l]; c.ksteps = c.chunkH / 32;
        c.gramBase = gBase;  gBase += 8 * c.nch * c.nt * c.nt;
        c.qformBase = qBase; qBase += 8 * c.nt;
    }

    TrParams tp;
    tp.m[0] = {fc1_w, wt1, 640, 512, 0};
    tp.m[1] = {fc2_w, wt2, 512, 512, 320};
    tp.m[2] = {fc3_w, wt3, 512, 128, 576};

    // ---- launches
    softmax_kernel<<<NLVL * NQ, 64, 0, stream>>>(sp);
    wtrans_kernel<<<640, 256, 0, stream>>>(tp);
    hipMemsetAsync(quad, 0, (size_t)NLVL * 8 * NQ * sizeof(float), stream);
    gram_kernel<<<gBase, 256, 0, stream>>>(gp);            // 704 blocks
    qform_kernel<<<qBase, 256, 0, stream>>>(gp, quad);     // 96 blocks
    head_kernel<<<8, 512, 0, stream>>>(quad, wt1, fc1_b, wt2, fc2_b, wt3, fc3_b,
                                       (float*)d_out);
}